// Round 1
// baseline (76972.260 us; speedup 1.0000x reference)
//
#include <hip/hip_runtime.h>
#include <cstddef>
#include <cstdint>

#define H      1024
#define HP     1025
#define OUTD   32
#define ACTD   8
#define BATCH  128
#define SEQLEN 256
#define TSTEPS 255
#define G3     3072
#define LOG2PI 1.8378770664093453f

// ---------------------------------------------------------------------------
// Generic tiled f32 GEMM: C[M,N] = act(A[M,K] @ B[N,K]^T + bias[N])
// Both A and B are K-major (row-major with K as the inner dim), which matches
// every GEMM in this net (x @ w.T). 32x32 tiles, 256 threads, 4 outputs/thread.
// ACTMODE: 0 = none, 1 = relu, 2 = tanh
// ---------------------------------------------------------------------------
template <int ACTMODE>
__global__ __launch_bounds__(256) void gemm_nt(const float* __restrict__ A,
                                               const float* __restrict__ Bm,
                                               const float* __restrict__ bias,
                                               float* __restrict__ C,
                                               int M, int N, int K) {
  __shared__ float As[32][33];
  __shared__ float Bs[32][33];
  const int bm = blockIdx.y, bn = blockIdx.x;
  const int t = threadIdx.x;
  const int tr = t >> 5, tc = t & 31;
  float acc0 = 0.f, acc1 = 0.f, acc2 = 0.f, acc3 = 0.f;
  for (int k0 = 0; k0 < K; k0 += 32) {
#pragma unroll
    for (int e = 0; e < 4; ++e) {
      int idx = t + e * 256;
      int r = idx >> 5, c = idx & 31;
      As[r][c] = A[(size_t)(bm * 32 + r) * K + (k0 + c)];
      Bs[r][c] = Bm[(size_t)(bn * 32 + r) * K + (k0 + c)];
    }
    __syncthreads();
#pragma unroll
    for (int kk = 0; kk < 32; ++kk) {
      float bv = Bs[tc][kk];
      acc0 = fmaf(As[tr][kk], bv, acc0);
      acc1 = fmaf(As[tr + 8][kk], bv, acc1);
      acc2 = fmaf(As[tr + 16][kk], bv, acc2);
      acc3 = fmaf(As[tr + 24][kk], bv, acc3);
    }
    __syncthreads();
  }
  const float bv = bias[bn * 32 + tc];
  float vals[4] = {acc0 + bv, acc1 + bv, acc2 + bv, acc3 + bv};
#pragma unroll
  for (int i2 = 0; i2 < 4; ++i2) {
    float v = vals[i2];
    if (ACTMODE == 1) v = v > 0.f ? v : 0.f;
    if (ACTMODE == 2) v = tanhf(v);
    C[(size_t)(bm * 32 + tr + i2 * 8) * N + (bn * 32 + tc)] = v;
  }
}

// ---------------------------------------------------------------------------
// GRU gate fusion. gh (B x 3H) already holds h_prev @ w_hh^T + b_hh.
// Computes gi on the fly (K=8), applies gates, writes f[b, 0:H] = hc and
// f[b, H] = 1.0 (the bias column of the Bayesian layer).
// ---------------------------------------------------------------------------
__global__ __launch_bounds__(256) void gru_gates(const float* __restrict__ gh,
                                                 const float* __restrict__ a_t,
                                                 const float* __restrict__ w_ih,
                                                 const float* __restrict__ b_ih,
                                                 const float* __restrict__ h,
                                                 float* __restrict__ f) {
  const int idx = blockIdx.x * 256 + threadIdx.x;  // 0 .. B*H-1
  const int b = idx >> 10;
  const int i = idx & (H - 1);
  float av[ACTD];
#pragma unroll
  for (int k = 0; k < ACTD; ++k) av[k] = a_t[b * ACTD + k];
  float gir = b_ih[i], giz = b_ih[H + i], gin = b_ih[2 * H + i];
#pragma unroll
  for (int k = 0; k < ACTD; ++k) {
    gir = fmaf(av[k], w_ih[(size_t)i * ACTD + k], gir);
    giz = fmaf(av[k], w_ih[(size_t)(H + i) * ACTD + k], giz);
    gin = fmaf(av[k], w_ih[(size_t)(2 * H + i) * ACTD + k], gin);
  }
  const float ghr = gh[(size_t)b * G3 + i];
  const float ghz = gh[(size_t)b * G3 + H + i];
  const float ghn = gh[(size_t)b * G3 + 2 * H + i];
  const float r = 1.f / (1.f + expf(-(gir + ghr)));
  const float z = 1.f / (1.f + expf(-(giz + ghz)));
  const float n = tanhf(gin + r * ghn);
  const float hp = h[(size_t)b * H + i];
  f[(size_t)b * HP + i] = (1.f - z) * n + z * hp;
  if (i == 0) f[(size_t)b * HP + H] = 1.0f;
}

// ---------------------------------------------------------------------------
// The dominant kernel: nh[b,i] = tanh( sum_j (mu[i,j] + sig[i,j]*eps[b,i,j]) * f[b,j] )
// One wave per (b, i) row; 4 waves/block share f[b] in LDS.
// Row pitch is 1025 floats (4100 B, == 4 mod 16), so we peel a wave-uniform
// lead of (4 - i%4)%4 elements to get 16B-aligned float4 streams for the
// three global operands, plus a <=3 element tail.
// Block order: b fastest, so 128 consecutive blocks share mu/sigma rows (L2 hit).
// ---------------------------------------------------------------------------
__global__ __launch_bounds__(256) void wmatvec(const float* __restrict__ W_eps,
                                               const float* __restrict__ W_mu,
                                               const float* __restrict__ sigma,
                                               const float* __restrict__ f,
                                               float* __restrict__ nh) {
  const int b = blockIdx.x & (BATCH - 1);
  const int ichunk = blockIdx.x >> 7;
  const int wave = threadIdx.x >> 6;
  const int lane = threadIdx.x & 63;
  const int i = ichunk * 4 + wave;

  __shared__ __align__(16) float fs[HP];
  for (int idx = threadIdx.x; idx < HP; idx += 256) fs[idx] = f[(size_t)b * HP + idx];
  __syncthreads();

  const float* er = W_eps + ((size_t)b * H + i) * HP;
  const float* mr = W_mu + (size_t)i * HP;
  const float* sr = sigma + (size_t)i * HP;

  const int pre = (4 - (i & 3)) & 3;  // elements until 16B alignment (same for all 3 streams)
  float acc = 0.f;
  if (lane < pre) {
    float w = fmaf(sr[lane], er[lane], mr[lane]);
    acc = w * fs[lane];
  }
  const int f4count = (HP - pre) >> 2;  // 255 or 256
  const int tail = (HP - pre) & 3;
  const float4* e4 = (const float4*)(er + pre);
  const float4* m4 = (const float4*)(mr + pre);
  const float4* s4 = (const float4*)(sr + pre);
#pragma unroll
  for (int c = 0; c < 4; ++c) {
    int idx = c * 64 + lane;
    if (idx < f4count) {
      float4 e = e4[idx];
      float4 m = m4[idx];
      float4 s = s4[idx];
      int j = pre + idx * 4;
      acc = fmaf(fmaf(s.x, e.x, m.x), fs[j + 0], acc);
      acc = fmaf(fmaf(s.y, e.y, m.y), fs[j + 1], acc);
      acc = fmaf(fmaf(s.z, e.z, m.z), fs[j + 2], acc);
      acc = fmaf(fmaf(s.w, e.w, m.w), fs[j + 3], acc);
    }
  }
  const int tstart = pre + f4count * 4;
  if (lane < tail) {
    int j = tstart + lane;
    float w = fmaf(sr[j], er[j], mr[j]);
    acc = fmaf(w, fs[j], acc);
  }
#pragma unroll
  for (int off = 32; off > 0; off >>= 1) acc += __shfl_xor(acc, off, 64);
  if (lane == 0) nh[(size_t)b * H + i] = tanhf(acc);
}

// ---------------------------------------------------------------------------
// Output heads + log-likelihood accumulation. One block per batch element.
// mean = dec @ em_w^T + em_b ; lv = dec @ ev_w^T + ev_b ;
// ll = -0.5*( (tgt-mean)^2 * exp(-lv) + lv + log(2pi) ), summed into LL_acc.
// ---------------------------------------------------------------------------
__global__ __launch_bounds__(256) void heads_ll(const float* __restrict__ dec,
                                                const float* __restrict__ em_w,
                                                const float* __restrict__ em_b,
                                                const float* __restrict__ ev_w,
                                                const float* __restrict__ ev_b,
                                                const float* __restrict__ Xt1,
                                                float* __restrict__ LL_acc) {
  const int b = blockIdx.x;
  __shared__ float dsh[H];
  __shared__ float red[256];
  for (int j = threadIdx.x; j < H; j += 256) dsh[j] = dec[(size_t)b * H + j];
  __syncthreads();
  const int o = threadIdx.x & 31;
  const int which = (threadIdx.x >> 5) & 1;  // 0 = mean, 1 = logvar
  const int chunk = threadIdx.x >> 6;        // 0..3
  const float* wrow = (which ? ev_w : em_w) + (size_t)o * H;
  float s = 0.f;
  const int j0 = chunk * 256;
  for (int j = j0; j < j0 + 256; ++j) s = fmaf(dsh[j], wrow[j], s);
  red[threadIdx.x] = s;
  __syncthreads();
  if (threadIdx.x < 64) {
    red[threadIdx.x] = red[threadIdx.x] + red[threadIdx.x + 64] +
                       red[threadIdx.x + 128] + red[threadIdx.x + 192];
  }
  __syncthreads();
  float ll = 0.f;
  if (threadIdx.x < 32) {
    float mean = red[threadIdx.x] + em_b[threadIdx.x];
    float lv = red[threadIdx.x + 32] + ev_b[threadIdx.x];
    float tgt = Xt1[(size_t)b * OUTD + threadIdx.x];
    float d = tgt - mean;
    ll = -0.5f * (d * d * expf(-lv) + lv + LOG2PI);
  }
#pragma unroll
  for (int off = 32; off > 0; off >>= 1) ll += __shfl_xor(ll, off, 64);
  if (threadIdx.x == 0) atomicAdd(LL_acc, ll);
}

// ---------------------------------------------------------------------------
// One-time: sigma = exp(0.5*W_logvar) and the KL reduction.
// ---------------------------------------------------------------------------
__global__ __launch_bounds__(256) void kl_sigma(const float* __restrict__ Wlv,
                                                const float* __restrict__ pmu,
                                                const float* __restrict__ plv,
                                                const float* __restrict__ Wmu,
                                                float* __restrict__ sigma,
                                                float* __restrict__ KL_acc) {
  const int idx = blockIdx.x * 256 + threadIdx.x;
  float v = 0.f;
  if (idx < H * HP) {
    float qlv = Wlv[idx];
    sigma[idx] = expf(0.5f * qlv);
    float var_q = expf(qlv);
    float p_lv = plv[idx];
    float var_p = expf(p_lv);
    float dmu = Wmu[idx] - pmu[idx];
    v = 0.5f * (p_lv - qlv) + (var_q + dmu * dmu) / (2.f * var_p) - 0.5f;
  }
  __shared__ float red[256];
  red[threadIdx.x] = v;
  __syncthreads();
  for (int s = 128; s > 0; s >>= 1) {
    if (threadIdx.x < s) red[threadIdx.x] += red[threadIdx.x + s];
    __syncthreads();
  }
  if (threadIdx.x == 0) atomicAdd(KL_acc, red[0]);
}

__global__ void finalize(const float* __restrict__ acc, float* __restrict__ out) {
  const float LLn = acc[0] / (float)BATCH;
  const float KLn = acc[1] / ((float)TSTEPS * (float)BATCH);
  out[0] = LLn - KLn;
  out[1] = LLn;
  out[2] = KLn;
}

// ---------------------------------------------------------------------------
extern "C" void kernel_launch(void* const* d_in, const int* in_sizes, int n_in,
                              void* d_out, int out_size, void* d_ws, size_t ws_size,
                              hipStream_t stream) {
  const float* X      = (const float*)d_in[0];
  const float* A      = (const float*)d_in[1];
  const float* W_eps  = (const float*)d_in[2];
  const float* W_mu   = (const float*)d_in[3];
  const float* W_lv   = (const float*)d_in[4];
  const float* pW_mu  = (const float*)d_in[5];
  const float* pW_lv  = (const float*)d_in[6];
  const float* enc_w1 = (const float*)d_in[7];
  const float* enc_b1 = (const float*)d_in[8];
  const float* enc_w2 = (const float*)d_in[9];
  const float* enc_b2 = (const float*)d_in[10];
  const float* gw_ih  = (const float*)d_in[11];
  const float* gw_hh  = (const float*)d_in[12];
  const float* gb_ih  = (const float*)d_in[13];
  const float* gb_hh  = (const float*)d_in[14];
  const float* dec_w  = (const float*)d_in[15];
  const float* dec_b  = (const float*)d_in[16];
  const float* em_w   = (const float*)d_in[17];
  const float* em_b   = (const float*)d_in[18];
  const float* ev_w   = (const float*)d_in[19];
  const float* ev_b   = (const float*)d_in[20];
  float* out = (float*)d_out;

  // workspace layout (floats)
  float* ws = (float*)d_ws;
  const size_t off_sigma = 0;                       // H*HP
  const size_t off_h     = off_sigma + (size_t)H * HP;   // B*H
  const size_t off_f     = off_h + (size_t)BATCH * H;    // B*HP
  const size_t off_gh    = off_f + (size_t)BATCH * HP;   // B*3H (also reused for enc hidden)
  const size_t off_dec   = off_gh + (size_t)BATCH * G3;  // B*H
  const size_t off_acc   = off_dec + (size_t)BATCH * H;  // [LL, KL]
  float* sigma = ws + off_sigma;
  float* hbuf  = ws + off_h;
  float* fbuf  = ws + off_f;
  float* ghbuf = ws + off_gh;
  float* decb  = ws + off_dec;
  float* accb  = ws + off_acc;

  hipMemsetAsync(accb, 0, 2 * sizeof(float), stream);

  // sigma + KL (once)
  {
    int nblk = (H * HP + 255) / 256;
    kl_sigma<<<nblk, 256, 0, stream>>>(W_lv, pW_mu, pW_lv, W_mu, sigma, accb + 1);
  }
  // encoder: r = relu(X0 @ enc_w1^T + b1)  (reuse ghbuf), h = tanh(r @ enc_w2^T + b2)
  gemm_nt<1><<<dim3(H / 32, BATCH / 32), 256, 0, stream>>>(X, enc_w1, enc_b1, ghbuf,
                                                           BATCH, H, OUTD);
  gemm_nt<2><<<dim3(H / 32, BATCH / 32), 256, 0, stream>>>(ghbuf, enc_w2, enc_b2, hbuf,
                                                           BATCH, H, H);

  for (int t = 0; t < TSTEPS; ++t) {
    const float* a_t = A + (size_t)t * BATCH * ACTD;
    const float* Xt1 = X + (size_t)(t + 1) * BATCH * OUTD;
    // gh = h @ w_hh^T + b_hh
    gemm_nt<0><<<dim3(G3 / 32, BATCH / 32), 256, 0, stream>>>(hbuf, gw_hh, gb_hh, ghbuf,
                                                              BATCH, G3, H);
    // gates -> f (= [hc, 1])
    gru_gates<<<(BATCH * H) / 256, 256, 0, stream>>>(ghbuf, a_t, gw_ih, gb_ih, hbuf, fbuf);
    // nh = tanh(W f) -> overwrite h
    wmatvec<<<(H / 4) * BATCH, 256, 0, stream>>>(W_eps, W_mu, sigma, fbuf, hbuf);
    // dec = relu(nh @ dec_w^T + dec_b)
    gemm_nt<1><<<dim3(H / 32, BATCH / 32), 256, 0, stream>>>(hbuf, dec_w, dec_b, decb,
                                                             BATCH, H, H);
    // heads + LL accumulation
    heads_ll<<<BATCH, 256, 0, stream>>>(decb, em_w, em_b, ev_w, ev_b, Xt1, accb);
  }

  finalize<<<1, 1, 0, stream>>>(accb, out);
}

// Round 2
// 32174.228 us; speedup vs baseline: 2.3924x; 2.3924x over previous
//
#include <hip/hip_runtime.h>
#include <cstddef>
#include <cstdint>

#define H      1024
#define HP     1025
#define OUTD   32
#define ACTD   8
#define BATCH  128
#define TSTEPS 255
#define G3     3072
#define LOG2PI 1.8378770664093453f

typedef __bf16 bf16x8 __attribute__((ext_vector_type(8)));
typedef float  f32x4  __attribute__((ext_vector_type(4)));

__device__ __forceinline__ unsigned short f2bf(float x) {
  unsigned int u = __float_as_uint(x);
  unsigned int r = (u + 0x7fffu + ((u >> 16) & 1u)) >> 16;  // RNE
  return (unsigned short)r;
}
__device__ __forceinline__ float bflo(unsigned int u) { return __uint_as_float(u << 16); }
__device__ __forceinline__ float bfhi(unsigned int u) { return __uint_as_float(u & 0xffff0000u); }

// ---------------------------------------------------------------------------
// Naive f32 GEMM (encoder only, runs once): C = act(A[M,K] @ B[N,K]^T + bias)
// ---------------------------------------------------------------------------
template <int ACTMODE>
__global__ __launch_bounds__(256) void gemm_nt(const float* __restrict__ A,
                                               const float* __restrict__ Bm,
                                               const float* __restrict__ bias,
                                               float* __restrict__ C,
                                               int M, int N, int K) {
  __shared__ float As[32][33];
  __shared__ float Bs[32][33];
  const int bm = blockIdx.y, bn = blockIdx.x;
  const int t = threadIdx.x;
  const int tr = t >> 5, tc = t & 31;
  float acc0 = 0.f, acc1 = 0.f, acc2 = 0.f, acc3 = 0.f;
  for (int k0 = 0; k0 < K; k0 += 32) {
#pragma unroll
    for (int e = 0; e < 4; ++e) {
      int idx = t + e * 256;
      int r = idx >> 5, c = idx & 31;
      As[r][c] = A[(size_t)(bm * 32 + r) * K + (k0 + c)];
      Bs[r][c] = Bm[(size_t)(bn * 32 + r) * K + (k0 + c)];
    }
    __syncthreads();
#pragma unroll
    for (int kk = 0; kk < 32; ++kk) {
      float bv = Bs[tc][kk];
      acc0 = fmaf(As[tr][kk], bv, acc0);
      acc1 = fmaf(As[tr + 8][kk], bv, acc1);
      acc2 = fmaf(As[tr + 16][kk], bv, acc2);
      acc3 = fmaf(As[tr + 24][kk], bv, acc3);
    }
    __syncthreads();
  }
  const float bv = bias[bn * 32 + tc];
  float vals[4] = {acc0 + bv, acc1 + bv, acc2 + bv, acc3 + bv};
#pragma unroll
  for (int i2 = 0; i2 < 4; ++i2) {
    float v = vals[i2];
    if (ACTMODE == 1) v = v > 0.f ? v : 0.f;
    if (ACTMODE == 2) v = tanhf(v);
    C[(size_t)(bm * 32 + tr + i2 * 8) * N + (bn * 32 + tc)] = v;
  }
}

// ---------------------------------------------------------------------------
// bf16 MFMA GEMM: C[M,N] = act(A[M,K]bf16 @ B[N,K]bf16^T + bias). One wave per
// 16x16 C-tile; 4 accumulator chains for MFMA ILP; direct 16B global loads
// (A is L2-resident, B rows reused 8x via L2).
// A-frag: lane holds A[m = lane&15][k = (lane>>4)*8 + j]; same for B rows.
// C/D: col = lane&15, row = (lane>>4)*4 + reg  (measured m89/m91).
// ---------------------------------------------------------------------------
template <int ACTMODE>
__global__ __launch_bounds__(64) void gemm_mfma(const unsigned short* __restrict__ A,
                                                const unsigned short* __restrict__ B,
                                                const float* __restrict__ bias,
                                                float* __restrict__ C,
                                                int N, int K) {
  const int lane = threadIdx.x;
  const int m0 = blockIdx.y * 16;
  const int n0 = blockIdx.x * 16;
  const int row = lane & 15;
  const int kq = lane >> 4;  // 0..3
  const unsigned short* ap = A + (size_t)(m0 + row) * K + kq * 8;
  const unsigned short* bp = B + (size_t)(n0 + row) * K + kq * 8;
  f32x4 acc[4];
#pragma unroll
  for (int u = 0; u < 4; ++u) acc[u] = {0.f, 0.f, 0.f, 0.f};
  for (int k0 = 0; k0 < K; k0 += 128) {
#pragma unroll
    for (int u = 0; u < 4; ++u) {
      bf16x8 a = *(const bf16x8*)(const void*)(ap + k0 + u * 32);
      bf16x8 b = *(const bf16x8*)(const void*)(bp + k0 + u * 32);
      acc[u] = __builtin_amdgcn_mfma_f32_16x16x32_bf16(a, b, acc[u], 0, 0, 0);
    }
  }
  f32x4 d = acc[0] + acc[1] + acc[2] + acc[3];
  const int col = lane & 15;
  const int rbase = (lane >> 4) * 4;
  const float bv = bias[n0 + col];
#pragma unroll
  for (int r = 0; r < 4; ++r) {
    float v = d[r] + bv;
    if (ACTMODE == 1) v = v > 0.f ? v : 0.f;
    C[(size_t)(m0 + rbase + r) * N + (n0 + col)] = v;
  }
}

// ---------------------------------------------------------------------------
// GRU gate fusion (unchanged from round 1; writes f[b,0:H]=hc, f[b,H]=1).
// ---------------------------------------------------------------------------
__global__ __launch_bounds__(256) void gru_gates(const float* __restrict__ gh,
                                                 const float* __restrict__ a_t,
                                                 const float* __restrict__ w_ih,
                                                 const float* __restrict__ b_ih,
                                                 const float* __restrict__ h,
                                                 float* __restrict__ f) {
  const int idx = blockIdx.x * 256 + threadIdx.x;
  const int b = idx >> 10;
  const int i = idx & (H - 1);
  float av[ACTD];
#pragma unroll
  for (int k = 0; k < ACTD; ++k) av[k] = a_t[b * ACTD + k];
  float gir = b_ih[i], giz = b_ih[H + i], gin = b_ih[2 * H + i];
#pragma unroll
  for (int k = 0; k < ACTD; ++k) {
    gir = fmaf(av[k], w_ih[(size_t)i * ACTD + k], gir);
    giz = fmaf(av[k], w_ih[(size_t)(H + i) * ACTD + k], giz);
    gin = fmaf(av[k], w_ih[(size_t)(2 * H + i) * ACTD + k], gin);
  }
  const float ghr = gh[(size_t)b * G3 + i];
  const float ghz = gh[(size_t)b * G3 + H + i];
  const float ghn = gh[(size_t)b * G3 + 2 * H + i];
  const float r = 1.f / (1.f + expf(-(gir + ghr)));
  const float z = 1.f / (1.f + expf(-(giz + ghz)));
  const float n = tanhf(gin + r * ghn);
  const float hp = h[(size_t)b * H + i];
  f[(size_t)b * HP + i] = (1.f - z) * n + z * hp;
  if (i == 0) f[(size_t)b * HP + H] = 1.0f;
}

// ---------------------------------------------------------------------------
// One-time: Wc[b,i,0:1024] = bf16(mu + sigma*eps) with aligned pitch 1024,
// last column (j=1024) in a separate array. block = one (b,i) row.
// ---------------------------------------------------------------------------
__global__ __launch_bounds__(256) void gen_w(const float* __restrict__ eps,
                                             const float* __restrict__ mu,
                                             const float* __restrict__ sig,
                                             unsigned short* __restrict__ Wm,
                                             unsigned short* __restrict__ Wlast) {
  const size_t rowid = blockIdx.x;      // b*H + i
  const int i = (int)(rowid & (H - 1));
  const int jq = threadIdx.x;           // 0..255, each handles 4 elems
  const float* er = eps + rowid * HP + jq * 4;
  const float* mr = mu + (size_t)i * HP + jq * 4;
  const float* sr = sig + (size_t)i * HP + jq * 4;
  ushort4 o;
  o.x = f2bf(fmaf(sr[0], er[0], mr[0]));
  o.y = f2bf(fmaf(sr[1], er[1], mr[1]));
  o.z = f2bf(fmaf(sr[2], er[2], mr[2]));
  o.w = f2bf(fmaf(sr[3], er[3], mr[3]));
  *(ushort4*)(Wm + rowid * 1024 + jq * 4) = o;
  if (jq == 255) Wlast[rowid] = f2bf(fmaf(sr[4], er[4], mr[4]));  // j = 1024
}

__global__ __launch_bounds__(256) void cvt_bf16(const float* __restrict__ src,
                                                unsigned short* __restrict__ dst, int n) {
  int i = blockIdx.x * 256 + threadIdx.x;
  if (i < n) dst[i] = f2bf(src[i]);
}

// ---------------------------------------------------------------------------
// Dominant kernel (bf16 W): nh[b,i] = tanh( sum_j Wc[b,i,j]*f[b,j] + Wlast[b,i] )
// One wave per row, 4 rows per block sharing f[b] in LDS.
// f stored split-half swizzled so both ds_read_b128 per lane are lane-stride
// 16B (minimal-conflict). W loads: uint4 = 8 bf16 = 16B per lane.
// Writes h (f32) and hb (bf16 mirror for the MFMA GEMMs).
// ---------------------------------------------------------------------------
__global__ __launch_bounds__(256) void wmatvec_bf16(const unsigned int* __restrict__ Wm,
                                                    const unsigned short* __restrict__ Wlast,
                                                    const float* __restrict__ f,
                                                    float* __restrict__ h,
                                                    unsigned short* __restrict__ hb) {
  const int b = blockIdx.x & (BATCH - 1);
  const int ichunk = blockIdx.x >> 7;
  const int wave = threadIdx.x >> 6;
  const int lane = threadIdx.x & 63;
  const int i = ichunk * 4 + wave;

  // swizzled f: for j = 8q+d: fsw[(d>>2)*512 + q*4 + (d&3)]
  __shared__ __align__(16) float fsw[1024];
  for (int idx = threadIdx.x; idx < 1024; idx += 256) {
    int q = idx >> 3, d = idx & 7;
    fsw[((d >> 2) << 9) + (q << 2) + (d & 3)] = f[(size_t)b * HP + idx];
  }
  __syncthreads();

  const size_t rowid = (size_t)b * H + i;
  const uint4* wrow = (const uint4*)(const void*)(Wm + rowid * 256);  // 256 uints/row... (1024 bf16 = 512 uints)
  // NOTE: Wm is uint*; row is 512 uints = 128 uint4.
  const uint4* wr4 = (const uint4*)(const void*)(Wm + rowid * 512);
  (void)wrow;
  float acc = 0.f;
#pragma unroll
  for (int c = 0; c < 2; ++c) {
    const int q = c * 64 + lane;  // chunk of 8 elements
    uint4 w = wr4[q];
    float4 flo = *(const float4*)(const void*)(fsw + (q << 2));
    float4 fhi = *(const float4*)(const void*)(fsw + 512 + (q << 2));
    acc = fmaf(bflo(w.x), flo.x, acc);
    acc = fmaf(bfhi(w.x), flo.y, acc);
    acc = fmaf(bflo(w.y), flo.z, acc);
    acc = fmaf(bfhi(w.y), flo.w, acc);
    acc = fmaf(bflo(w.z), fhi.x, acc);
    acc = fmaf(bfhi(w.z), fhi.y, acc);
    acc = fmaf(bflo(w.w), fhi.z, acc);
    acc = fmaf(bfhi(w.w), fhi.w, acc);
  }
#pragma unroll
  for (int off = 32; off > 0; off >>= 1) acc += __shfl_xor(acc, off, 64);
  if (lane == 0) {
    acc += __uint_as_float(((unsigned int)Wlast[rowid]) << 16);  // f[H] == 1
    float v = tanhf(acc);
    h[rowid] = v;
    hb[rowid] = f2bf(v);
  }
}

// ---------------------------------------------------------------------------
// Fallback (ws too small): round-1 f32 eps-streaming matvec, + bf16 mirror.
// ---------------------------------------------------------------------------
__global__ __launch_bounds__(256) void wmatvec_f32(const float* __restrict__ W_eps,
                                                   const float* __restrict__ W_mu,
                                                   const float* __restrict__ sigma,
                                                   const float* __restrict__ f,
                                                   float* __restrict__ h,
                                                   unsigned short* __restrict__ hb) {
  const int b = blockIdx.x & (BATCH - 1);
  const int ichunk = blockIdx.x >> 7;
  const int wave = threadIdx.x >> 6;
  const int lane = threadIdx.x & 63;
  const int i = ichunk * 4 + wave;
  __shared__ __align__(16) float fs[HP];
  for (int idx = threadIdx.x; idx < HP; idx += 256) fs[idx] = f[(size_t)b * HP + idx];
  __syncthreads();
  const float* er = W_eps + ((size_t)b * H + i) * HP;
  const float* mr = W_mu + (size_t)i * HP;
  const float* sr = sigma + (size_t)i * HP;
  const int pre = (4 - (i & 3)) & 3;
  float acc = 0.f;
  if (lane < pre) acc = fmaf(sr[lane], er[lane], mr[lane]) * fs[lane];
  const int f4count = (HP - pre) >> 2;
  const int tail = (HP - pre) & 3;
  const float4* e4 = (const float4*)(er + pre);
  const float4* m4 = (const float4*)(mr + pre);
  const float4* s4 = (const float4*)(sr + pre);
#pragma unroll
  for (int c = 0; c < 4; ++c) {
    int idx = c * 64 + lane;
    if (idx < f4count) {
      float4 e = e4[idx];
      float4 m = m4[idx];
      float4 s = s4[idx];
      int j = pre + idx * 4;
      acc = fmaf(fmaf(s.x, e.x, m.x), fs[j + 0], acc);
      acc = fmaf(fmaf(s.y, e.y, m.y), fs[j + 1], acc);
      acc = fmaf(fmaf(s.z, e.z, m.z), fs[j + 2], acc);
      acc = fmaf(fmaf(s.w, e.w, m.w), fs[j + 3], acc);
    }
  }
  const int tstart = pre + f4count * 4;
  if (lane < tail) {
    int j = tstart + lane;
    acc = fmaf(fmaf(sr[j], er[j], mr[j]), fs[j], acc);
  }
#pragma unroll
  for (int off = 32; off > 0; off >>= 1) acc += __shfl_xor(acc, off, 64);
  if (lane == 0) {
    float v = tanhf(acc);
    h[(size_t)b * H + i] = v;
    hb[(size_t)b * H + i] = f2bf(v);
  }
}

// ---------------------------------------------------------------------------
// Heads + LL (unchanged from round 1).
// ---------------------------------------------------------------------------
__global__ __launch_bounds__(256) void heads_ll(const float* __restrict__ dec,
                                                const float* __restrict__ em_w,
                                                const float* __restrict__ em_b,
                                                const float* __restrict__ ev_w,
                                                const float* __restrict__ ev_b,
                                                const float* __restrict__ Xt1,
                                                float* __restrict__ LL_acc) {
  const int b = blockIdx.x;
  __shared__ float dsh[H];
  __shared__ float red[256];
  for (int j = threadIdx.x; j < H; j += 256) dsh[j] = dec[(size_t)b * H + j];
  __syncthreads();
  const int o = threadIdx.x & 31;
  const int which = (threadIdx.x >> 5) & 1;
  const int chunk = threadIdx.x >> 6;
  const float* wrow = (which ? ev_w : em_w) + (size_t)o * H;
  float s = 0.f;
  const int j0 = chunk * 256;
  for (int j = j0; j < j0 + 256; ++j) s = fmaf(dsh[j], wrow[j], s);
  red[threadIdx.x] = s;
  __syncthreads();
  if (threadIdx.x < 64) {
    red[threadIdx.x] = red[threadIdx.x] + red[threadIdx.x + 64] +
                       red[threadIdx.x + 128] + red[threadIdx.x + 192];
  }
  __syncthreads();
  float ll = 0.f;
  if (threadIdx.x < 32) {
    float mean = red[threadIdx.x] + em_b[threadIdx.x];
    float lv = red[threadIdx.x + 32] + ev_b[threadIdx.x];
    float tgt = Xt1[(size_t)b * OUTD + threadIdx.x];
    float d = tgt - mean;
    ll = -0.5f * (d * d * expf(-lv) + lv + LOG2PI);
  }
#pragma unroll
  for (int off = 32; off > 0; off >>= 1) ll += __shfl_xor(ll, off, 64);
  if (threadIdx.x == 0) atomicAdd(LL_acc, ll);
}

// ---------------------------------------------------------------------------
// sigma = exp(0.5*W_logvar) + KL reduction (unchanged).
// ---------------------------------------------------------------------------
__global__ __launch_bounds__(256) void kl_sigma(const float* __restrict__ Wlv,
                                                const float* __restrict__ pmu,
                                                const float* __restrict__ plv,
                                                const float* __restrict__ Wmu,
                                                float* __restrict__ sigma,
                                                float* __restrict__ KL_acc) {
  const int idx = blockIdx.x * 256 + threadIdx.x;
  float v = 0.f;
  if (idx < H * HP) {
    float qlv = Wlv[idx];
    sigma[idx] = expf(0.5f * qlv);
    float var_q = expf(qlv);
    float p_lv = plv[idx];
    float var_p = expf(p_lv);
    float dmu = Wmu[idx] - pmu[idx];
    v = 0.5f * (p_lv - qlv) + (var_q + dmu * dmu) / (2.f * var_p) - 0.5f;
  }
  __shared__ float red[256];
  red[threadIdx.x] = v;
  __syncthreads();
  for (int s = 128; s > 0; s >>= 1) {
    if (threadIdx.x < s) red[threadIdx.x] += red[threadIdx.x + s];
    __syncthreads();
  }
  if (threadIdx.x == 0) atomicAdd(KL_acc, red[0]);
}

__global__ void finalize(const float* __restrict__ acc, float* __restrict__ out) {
  const float LLn = acc[0] / (float)BATCH;
  const float KLn = acc[1] / ((float)TSTEPS * (float)BATCH);
  out[0] = LLn - KLn;
  out[1] = LLn;
  out[2] = KLn;
}

// ---------------------------------------------------------------------------
extern "C" void kernel_launch(void* const* d_in, const int* in_sizes, int n_in,
                              void* d_out, int out_size, void* d_ws, size_t ws_size,
                              hipStream_t stream) {
  const float* X      = (const float*)d_in[0];
  const float* A      = (const float*)d_in[1];
  const float* W_eps  = (const float*)d_in[2];
  const float* W_mu   = (const float*)d_in[3];
  const float* W_lv   = (const float*)d_in[4];
  const float* pW_mu  = (const float*)d_in[5];
  const float* pW_lv  = (const float*)d_in[6];
  const float* enc_w1 = (const float*)d_in[7];
  const float* enc_b1 = (const float*)d_in[8];
  const float* enc_w2 = (const float*)d_in[9];
  const float* enc_b2 = (const float*)d_in[10];
  const float* gw_ih  = (const float*)d_in[11];
  const float* gw_hh  = (const float*)d_in[12];
  const float* gb_ih  = (const float*)d_in[13];
  const float* gb_hh  = (const float*)d_in[14];
  const float* dec_w  = (const float*)d_in[15];
  const float* dec_b  = (const float*)d_in[16];
  const float* em_w   = (const float*)d_in[17];
  const float* em_b   = (const float*)d_in[18];
  const float* ev_w   = (const float*)d_in[19];
  const float* ev_b   = (const float*)d_in[20];
  float* out = (float*)d_out;

  char* base = (char*)d_ws;
  size_t off = 0;
  auto alloc = [&](size_t bytes) -> void* {
    void* p = base + off;
    off += (bytes + 255) & ~(size_t)255;
    return p;
  };
  float* sigma          = (float*)alloc((size_t)H * HP * 4);
  float* hbuf           = (float*)alloc((size_t)BATCH * H * 4);
  unsigned short* hb    = (unsigned short*)alloc((size_t)BATCH * H * 2);
  float* fbuf           = (float*)alloc((size_t)BATCH * HP * 4);
  float* ghbuf          = (float*)alloc((size_t)BATCH * G3 * 4);
  float* decb           = (float*)alloc((size_t)BATCH * H * 4);
  float* accb           = (float*)alloc(2 * 4);
  unsigned short* gwhhb = (unsigned short*)alloc((size_t)G3 * H * 2);
  unsigned short* decwb = (unsigned short*)alloc((size_t)H * H * 2);
  unsigned short* Wlast = (unsigned short*)alloc((size_t)BATCH * H * 2);
  unsigned short* Wm    = (unsigned short*)alloc((size_t)BATCH * H * 1024 * 2);
  const bool useBF16W = (ws_size >= off);

  hipMemsetAsync(accb, 0, 2 * sizeof(float), stream);

  kl_sigma<<<(H * HP + 255) / 256, 256, 0, stream>>>(W_lv, pW_mu, pW_lv, W_mu, sigma, accb + 1);
  cvt_bf16<<<(G3 * H) / 256, 256, 0, stream>>>(gw_hh, gwhhb, G3 * H);
  cvt_bf16<<<(H * H) / 256, 256, 0, stream>>>(dec_w, decwb, H * H);
  if (useBF16W) {
    gen_w<<<BATCH * H, 256, 0, stream>>>(W_eps, W_mu, sigma, Wm, Wlast);
  }

  // encoder
  gemm_nt<1><<<dim3(H / 32, BATCH / 32), 256, 0, stream>>>(X, enc_w1, enc_b1, ghbuf,
                                                           BATCH, H, OUTD);
  gemm_nt<2><<<dim3(H / 32, BATCH / 32), 256, 0, stream>>>(ghbuf, enc_w2, enc_b2, hbuf,
                                                           BATCH, H, H);
  cvt_bf16<<<(BATCH * H) / 256, 256, 0, stream>>>(hbuf, hb, BATCH * H);

  for (int t = 0; t < TSTEPS; ++t) {
    const float* a_t = A + (size_t)t * BATCH * ACTD;
    const float* Xt1 = X + (size_t)(t + 1) * BATCH * OUTD;
    gemm_mfma<0><<<dim3(G3 / 16, BATCH / 16), 64, 0, stream>>>(hb, gwhhb, gb_hh, ghbuf, G3, H);
    gru_gates<<<(BATCH * H) / 256, 256, 0, stream>>>(ghbuf, a_t, gw_ih, gb_ih, hbuf, fbuf);
    if (useBF16W) {
      wmatvec_bf16<<<(H / 4) * BATCH, 256, 0, stream>>>((const unsigned int*)Wm, Wlast,
                                                        fbuf, hbuf, hb);
    } else {
      wmatvec_f32<<<(H / 4) * BATCH, 256, 0, stream>>>(W_eps, W_mu, sigma, fbuf, hbuf, hb);
    }
    gemm_mfma<1><<<dim3(H / 16, BATCH / 16), 64, 0, stream>>>(hb, decwb, dec_b, decb, H, H);
    heads_ll<<<BATCH, 256, 0, stream>>>(decb, em_w, em_b, ev_w, ev_b, Xt1, accb);
  }

  finalize<<<1, 1, 0, stream>>>(accb, out);
}

// Round 3
// 21936.015 us; speedup vs baseline: 3.5089x; 1.4667x over previous
//
#include <hip/hip_runtime.h>
#include <cstddef>
#include <cstdint>

#define H      1024
#define HP     1025
#define OUTD   32
#define ACTD   8
#define BATCH  128
#define TSTEPS 255
#define G3     3072
#define LOG2PI 1.8378770664093453f

typedef __bf16 bf16x8 __attribute__((ext_vector_type(8)));
typedef float  f32x4  __attribute__((ext_vector_type(4)));
typedef unsigned int u32x4v __attribute__((ext_vector_type(4)));

__device__ __forceinline__ unsigned short f2bf(float x) {
  unsigned int u = __float_as_uint(x);
  unsigned int r = (u + 0x7fffu + ((u >> 16) & 1u)) >> 16;  // RNE
  return (unsigned short)r;
}
__device__ __forceinline__ float bflo(unsigned int u) { return __uint_as_float(u << 16); }
__device__ __forceinline__ float bfhi(unsigned int u) { return __uint_as_float(u & 0xffff0000u); }
__device__ __forceinline__ bf16x8 ldb8(const unsigned short* p) {
  return *(const bf16x8*)(const void*)p;
}

// ---------------------------------------------------------------------------
// Naive f32 GEMM (encoder only, runs once): C = act(A[M,K] @ B[N,K]^T + bias)
// ---------------------------------------------------------------------------
template <int ACTMODE>
__global__ __launch_bounds__(256) void gemm_nt(const float* __restrict__ A,
                                               const float* __restrict__ Bm,
                                               const float* __restrict__ bias,
                                               float* __restrict__ C,
                                               int M, int N, int K) {
  __shared__ float As[32][33];
  __shared__ float Bs[32][33];
  const int bm = blockIdx.y, bn = blockIdx.x;
  const int t = threadIdx.x;
  const int tr = t >> 5, tc = t & 31;
  float acc0 = 0.f, acc1 = 0.f, acc2 = 0.f, acc3 = 0.f;
  for (int k0 = 0; k0 < K; k0 += 32) {
#pragma unroll
    for (int e = 0; e < 4; ++e) {
      int idx = t + e * 256;
      int r = idx >> 5, c = idx & 31;
      As[r][c] = A[(size_t)(bm * 32 + r) * K + (k0 + c)];
      Bs[r][c] = Bm[(size_t)(bn * 32 + r) * K + (k0 + c)];
    }
    __syncthreads();
#pragma unroll
    for (int kk = 0; kk < 32; ++kk) {
      float bv = Bs[tc][kk];
      acc0 = fmaf(As[tr][kk], bv, acc0);
      acc1 = fmaf(As[tr + 8][kk], bv, acc1);
      acc2 = fmaf(As[tr + 16][kk], bv, acc2);
      acc3 = fmaf(As[tr + 24][kk], bv, acc3);
    }
    __syncthreads();
  }
  const float bv = bias[bn * 32 + tc];
  float vals[4] = {acc0 + bv, acc1 + bv, acc2 + bv, acc3 + bv};
#pragma unroll
  for (int i2 = 0; i2 < 4; ++i2) {
    float v = vals[i2];
    if (ACTMODE == 1) v = v > 0.f ? v : 0.f;
    if (ACTMODE == 2) v = tanhf(v);
    C[(size_t)(bm * 32 + tr + i2 * 8) * N + (bn * 32 + tc)] = v;
  }
}

// ---------------------------------------------------------------------------
// K1: fused per-step kernel, two block roles.
// Role A (blocks [0, nRoleA)): gh = h@w_hh^T (MFMA, gh stays in registers) +
//   GRU gates in the epilogue -> writes f[b, i] (pitch H; the implicit bias
//   column f[b,H]=1 is folded into K2 via Wlast).
// Role B (blocks >= nRoleA): dec = relu(h@dec_w^T+b) for a 16-batch x 256-col
//   slab, staged bf16 in LDS, then a second MFMA vs [em_w;ev_w] producing
//   partial mean/logvar sums -> atomicAdd into Pbuf[128][64].
// ---------------------------------------------------------------------------
__global__ __launch_bounds__(256) void step_fused(
    const unsigned short* __restrict__ hb, const float* __restrict__ hprev,
    const unsigned short* __restrict__ gwhhb, const float* __restrict__ w_ih,
    const float* __restrict__ b_ih, const float* __restrict__ gb_hh,
    const float* __restrict__ a_t, float* __restrict__ f,
    const unsigned short* __restrict__ decwb, const float* __restrict__ dec_b,
    const unsigned short* __restrict__ headwb, float* __restrict__ Pbuf,
    int nRoleA) {
  const int wv = threadIdx.x >> 6;
  const int lane = threadIdx.x & 63;
  const int row = lane & 15, kq = lane >> 4;
  const int col = lane & 15, rbase = (lane >> 4) * 4;
  __shared__ unsigned short decls[16][264];  // Role B staging (padded stride)

  if ((int)blockIdx.x < nRoleA) {
    // ---------------- Role A ----------------
    const int mt = blockIdx.x >> 4, ng = blockIdx.x & 15;
    const int b0 = mt * 16;
    const int i0 = (ng * 4 + wv) * 16;
    const unsigned short* ap = hb + (size_t)(b0 + row) * H + kq * 8;
    const unsigned short* bpr = gwhhb + (size_t)(i0 + row) * H + kq * 8;
    const unsigned short* bpz = bpr + (size_t)H * H;
    const unsigned short* bpn = bpr + 2 * (size_t)H * H;
    f32x4 ar0 = {0.f, 0.f, 0.f, 0.f}, ar1 = ar0, az0 = ar0, az1 = ar0, an0 = ar0, an1 = ar0;
    for (int k0 = 0; k0 < H; k0 += 64) {
      bf16x8 a0 = ldb8(ap + k0);
      bf16x8 a1 = ldb8(ap + k0 + 32);
      ar0 = __builtin_amdgcn_mfma_f32_16x16x32_bf16(a0, ldb8(bpr + k0), ar0, 0, 0, 0);
      ar1 = __builtin_amdgcn_mfma_f32_16x16x32_bf16(a1, ldb8(bpr + k0 + 32), ar1, 0, 0, 0);
      az0 = __builtin_amdgcn_mfma_f32_16x16x32_bf16(a0, ldb8(bpz + k0), az0, 0, 0, 0);
      az1 = __builtin_amdgcn_mfma_f32_16x16x32_bf16(a1, ldb8(bpz + k0 + 32), az1, 0, 0, 0);
      an0 = __builtin_amdgcn_mfma_f32_16x16x32_bf16(a0, ldb8(bpn + k0), an0, 0, 0, 0);
      an1 = __builtin_amdgcn_mfma_f32_16x16x32_bf16(a1, ldb8(bpn + k0 + 32), an1, 0, 0, 0);
    }
    f32x4 AR = ar0 + ar1, AZ = az0 + az1, AN = an0 + an1;
    const int i = i0 + col;
    const float bihr = b_ih[i], bihz = b_ih[H + i], bihn = b_ih[2 * H + i];
    const float bhr = gb_hh[i], bhz = gb_hh[H + i], bhn = gb_hh[2 * H + i];
    const float4* wi = (const float4*)(const void*)(w_ih + (size_t)i * ACTD);
    const float4* wzp = (const float4*)(const void*)(w_ih + (size_t)(H + i) * ACTD);
    const float4* wnp = (const float4*)(const void*)(w_ih + (size_t)(2 * H + i) * ACTD);
    const float4 wr0 = wi[0], wr1 = wi[1];
    const float4 wz0 = wzp[0], wz1 = wzp[1];
    const float4 wn0 = wnp[0], wn1 = wnp[1];
#pragma unroll
    for (int r = 0; r < 4; ++r) {
      const int b = b0 + rbase + r;
      const float4* at = (const float4*)(const void*)(a_t + (size_t)b * ACTD);
      const float4 a0 = at[0], a1 = at[1];
      float gir = bihr, giz = bihz, gin = bihn;
      gir = fmaf(a0.x, wr0.x, gir); gir = fmaf(a0.y, wr0.y, gir);
      gir = fmaf(a0.z, wr0.z, gir); gir = fmaf(a0.w, wr0.w, gir);
      gir = fmaf(a1.x, wr1.x, gir); gir = fmaf(a1.y, wr1.y, gir);
      gir = fmaf(a1.z, wr1.z, gir); gir = fmaf(a1.w, wr1.w, gir);
      giz = fmaf(a0.x, wz0.x, giz); giz = fmaf(a0.y, wz0.y, giz);
      giz = fmaf(a0.z, wz0.z, giz); giz = fmaf(a0.w, wz0.w, giz);
      giz = fmaf(a1.x, wz1.x, giz); giz = fmaf(a1.y, wz1.y, giz);
      giz = fmaf(a1.z, wz1.z, giz); giz = fmaf(a1.w, wz1.w, giz);
      gin = fmaf(a0.x, wn0.x, gin); gin = fmaf(a0.y, wn0.y, gin);
      gin = fmaf(a0.z, wn0.z, gin); gin = fmaf(a0.w, wn0.w, gin);
      gin = fmaf(a1.x, wn1.x, gin); gin = fmaf(a1.y, wn1.y, gin);
      gin = fmaf(a1.z, wn1.z, gin); gin = fmaf(a1.w, wn1.w, gin);
      const float rg = 1.f / (1.f + expf(-(gir + AR[r] + bhr)));
      const float zg = 1.f / (1.f + expf(-(giz + AZ[r] + bhz)));
      const float ng_ = tanhf(gin + rg * (AN[r] + bhn));
      const float hp = hprev[(size_t)b * H + i];
      f[(size_t)b * H + i] = (1.f - zg) * ng_ + zg * hp;
    }
    return;
  }

  // ---------------- Role B ----------------
  const int rb = (int)blockIdx.x - nRoleA;
  const int b0 = (rb >> 2) * 16;
  const int J0 = (rb & 3) * 256;
  const unsigned short* ap = hb + (size_t)(b0 + row) * H + kq * 8;
#pragma unroll
  for (int tt = 0; tt < 4; ++tt) {
    const int j0 = J0 + (wv * 4 + tt) * 16;
    const unsigned short* bp = decwb + (size_t)(j0 + row) * H + kq * 8;
    f32x4 c0 = {0.f, 0.f, 0.f, 0.f}, c1 = c0;
    for (int k0 = 0; k0 < H; k0 += 64) {
      c0 = __builtin_amdgcn_mfma_f32_16x16x32_bf16(ldb8(ap + k0), ldb8(bp + k0), c0, 0, 0, 0);
      c1 = __builtin_amdgcn_mfma_f32_16x16x32_bf16(ldb8(ap + k0 + 32), ldb8(bp + k0 + 32), c1, 0, 0, 0);
    }
    f32x4 d = c0 + c1;
    const float db = dec_b[j0 + col];
#pragma unroll
    for (int r = 0; r < 4; ++r) {
      float v = d[r] + db;
      v = v > 0.f ? v : 0.f;
      decls[rbase + r][j0 - J0 + col] = f2bf(v);
    }
  }
  __syncthreads();
  {
    const int o0 = wv * 16;
    const unsigned short* hp2 = headwb + (size_t)(o0 + row) * H + J0 + kq * 8;
    f32x4 c0 = {0.f, 0.f, 0.f, 0.f}, c1 = c0;
#pragma unroll
    for (int k0 = 0; k0 < 256; k0 += 64) {
      bf16x8 a0 = *(const bf16x8*)(const void*)&decls[row][k0 + kq * 8];
      bf16x8 a1 = *(const bf16x8*)(const void*)&decls[row][k0 + 32 + kq * 8];
      c0 = __builtin_amdgcn_mfma_f32_16x16x32_bf16(a0, ldb8(hp2 + k0), c0, 0, 0, 0);
      c1 = __builtin_amdgcn_mfma_f32_16x16x32_bf16(a1, ldb8(hp2 + k0 + 32), c1, 0, 0, 0);
    }
    f32x4 d = c0 + c1;
#pragma unroll
    for (int r = 0; r < 4; ++r)
      atomicAdd(&Pbuf[(size_t)(b0 + rbase + r) * 64 + o0 + col], d[r]);
  }
}

// ---------------------------------------------------------------------------
// K2: HBM streamer. Blocks [0,8192): 16 rows/block (4 waves x 4 rows); W
// prefetched (nontemporal) before the f->LDS fill so load latency hides.
// Block 8192: log-likelihood for the PREVIOUS step from Pbuf, then zero Pbuf.
// ---------------------------------------------------------------------------
__global__ __launch_bounds__(256) void wmatvec2(
    const u32x4v* __restrict__ Wm4, const unsigned short* __restrict__ Wlast,
    const float* __restrict__ f, float* __restrict__ h, unsigned short* __restrict__ hb,
    float* __restrict__ Pbuf, const float* __restrict__ em_b,
    const float* __restrict__ ev_b, const float* __restrict__ Xt,
    float* __restrict__ LL_acc, int llflag) {
  if (blockIdx.x >= 8192) {
    __shared__ float red[256];
    float ll = 0.f;
    if (llflag) {
      for (int it = threadIdx.x; it < BATCH * OUTD; it += 256) {
        const int b = it >> 5, o = it & 31;
        const float mean = Pbuf[b * 64 + o] + em_b[o];
        const float lv = Pbuf[b * 64 + 32 + o] + ev_b[o];
        const float tgt = Xt[b * OUTD + o];
        const float d = tgt - mean;
        ll += -0.5f * (d * d * expf(-lv) + lv + LOG2PI);
      }
    }
    red[threadIdx.x] = ll;
    __syncthreads();
    for (int s = 128; s > 0; s >>= 1) {
      if (threadIdx.x < s) red[threadIdx.x] += red[threadIdx.x + s];
      __syncthreads();
    }
    if (llflag && threadIdx.x == 0) atomicAdd(LL_acc, red[0]);
    __syncthreads();
    if (llflag)
      for (int it = threadIdx.x; it < BATCH * 64; it += 256) Pbuf[it] = 0.f;
    return;
  }
  const int b = blockIdx.x >> 6, ic = blockIdx.x & 63;
  const int wv = threadIdx.x >> 6, lane = threadIdx.x & 63;
  const size_t row0 = (size_t)b * H + ic * 16 + wv * 4;
  u32x4v wvv[4][2];
#pragma unroll
  for (int rr = 0; rr < 4; ++rr)
#pragma unroll
    for (int c = 0; c < 2; ++c)
      wvv[rr][c] = __builtin_nontemporal_load(Wm4 + (row0 + rr) * 128 + c * 64 + lane);
  __shared__ __align__(16) float fsw[1024];
  for (int idx = threadIdx.x; idx < 1024; idx += 256) {
    const int q = idx >> 3, d2 = idx & 7;
    fsw[((d2 >> 2) << 9) + (q << 2) + (d2 & 3)] = f[(size_t)b * H + idx];
  }
  __syncthreads();
  float acc[4] = {0.f, 0.f, 0.f, 0.f};
#pragma unroll
  for (int c = 0; c < 2; ++c) {
    const int q = c * 64 + lane;
    const float4 flo = *(const float4*)(const void*)(fsw + (q << 2));
    const float4 fhi = *(const float4*)(const void*)(fsw + 512 + (q << 2));
#pragma unroll
    for (int rr = 0; rr < 4; ++rr) {
      const u32x4v wq = wvv[rr][c];
      acc[rr] = fmaf(bflo(wq.x), flo.x, acc[rr]);
      acc[rr] = fmaf(bfhi(wq.x), flo.y, acc[rr]);
      acc[rr] = fmaf(bflo(wq.y), flo.z, acc[rr]);
      acc[rr] = fmaf(bfhi(wq.y), flo.w, acc[rr]);
      acc[rr] = fmaf(bflo(wq.z), fhi.x, acc[rr]);
      acc[rr] = fmaf(bfhi(wq.z), fhi.y, acc[rr]);
      acc[rr] = fmaf(bflo(wq.w), fhi.z, acc[rr]);
      acc[rr] = fmaf(bfhi(wq.w), fhi.w, acc[rr]);
    }
  }
#pragma unroll
  for (int rr = 0; rr < 4; ++rr) {
#pragma unroll
    for (int off = 32; off > 0; off >>= 1) acc[rr] += __shfl_xor(acc[rr], off, 64);
  }
  if (lane == 0) {
#pragma unroll
    for (int rr = 0; rr < 4; ++rr) {
      const size_t rid = row0 + rr;
      const float v = tanhf(acc[rr] + bflo((unsigned int)Wlast[rid]));
      h[rid] = v;
      hb[rid] = f2bf(v);
    }
  }
}

// ---------------------------------------------------------------------------
// One-time: Wc[b,i,0:1024] bf16 (pitch 1024), last column separate.
// ---------------------------------------------------------------------------
__global__ __launch_bounds__(256) void gen_w(const float* __restrict__ eps,
                                             const float* __restrict__ mu,
                                             const float* __restrict__ sig,
                                             unsigned short* __restrict__ Wm,
                                             unsigned short* __restrict__ Wlast) {
  const size_t rowid = blockIdx.x;  // b*H + i
  const int i = (int)(rowid & (H - 1));
  const int jq = threadIdx.x;
  const float* er = eps + rowid * HP + jq * 4;
  const float* mr = mu + (size_t)i * HP + jq * 4;
  const float* sr = sig + (size_t)i * HP + jq * 4;
  ushort4 o;
  o.x = f2bf(fmaf(sr[0], er[0], mr[0]));
  o.y = f2bf(fmaf(sr[1], er[1], mr[1]));
  o.z = f2bf(fmaf(sr[2], er[2], mr[2]));
  o.w = f2bf(fmaf(sr[3], er[3], mr[3]));
  *(ushort4*)(Wm + rowid * 1024 + jq * 4) = o;
  if (jq == 255) Wlast[rowid] = f2bf(fmaf(sr[4], er[4], mr[4]));
}

__global__ __launch_bounds__(256) void cvt_bf16(const float* __restrict__ src,
                                                unsigned short* __restrict__ dst, int n) {
  int i = blockIdx.x * 256 + threadIdx.x;
  if (i < n) dst[i] = f2bf(src[i]);
}

// ---------------------------------------------------------------------------
// sigma = exp(0.5*W_logvar) + KL reduction.
// ---------------------------------------------------------------------------
__global__ __launch_bounds__(256) void kl_sigma(const float* __restrict__ Wlv,
                                                const float* __restrict__ pmu,
                                                const float* __restrict__ plv,
                                                const float* __restrict__ Wmu,
                                                float* __restrict__ sigma,
                                                float* __restrict__ KL_acc) {
  const int idx = blockIdx.x * 256 + threadIdx.x;
  float v = 0.f;
  if (idx < H * HP) {
    float qlv = Wlv[idx];
    sigma[idx] = expf(0.5f * qlv);
    float var_q = expf(qlv);
    float p_lv = plv[idx];
    float var_p = expf(p_lv);
    float dmu = Wmu[idx] - pmu[idx];
    v = 0.5f * (p_lv - qlv) + (var_q + dmu * dmu) / (2.f * var_p) - 0.5f;
  }
  __shared__ float red[256];
  red[threadIdx.x] = v;
  __syncthreads();
  for (int s = 128; s > 0; s >>= 1) {
    if (threadIdx.x < s) red[threadIdx.x] += red[threadIdx.x + s];
    __syncthreads();
  }
  if (threadIdx.x == 0) atomicAdd(KL_acc, red[0]);
}

// Final: ll for t'=255 from Pbuf + assemble outputs.
__global__ __launch_bounds__(256) void finalize(const float* __restrict__ acc,
                                                const float* __restrict__ Pbuf,
                                                const float* __restrict__ em_b,
                                                const float* __restrict__ ev_b,
                                                const float* __restrict__ Xt,
                                                float* __restrict__ out) {
  __shared__ float red[256];
  float ll = 0.f;
  for (int it = threadIdx.x; it < BATCH * OUTD; it += 256) {
    const int b = it >> 5, o = it & 31;
    const float mean = Pbuf[b * 64 + o] + em_b[o];
    const float lv = Pbuf[b * 64 + 32 + o] + ev_b[o];
    const float tgt = Xt[b * OUTD + o];
    const float d = tgt - mean;
    ll += -0.5f * (d * d * expf(-lv) + lv + LOG2PI);
  }
  red[threadIdx.x] = ll;
  __syncthreads();
  for (int s = 128; s > 0; s >>= 1) {
    if (threadIdx.x < s) red[threadIdx.x] += red[threadIdx.x + s];
    __syncthreads();
  }
  if (threadIdx.x == 0) {
    const float LLn = (acc[0] + red[0]) / (float)BATCH;
    const float KLn = acc[1] / ((float)TSTEPS * (float)BATCH);
    out[0] = LLn - KLn;
    out[1] = LLn;
    out[2] = KLn;
  }
}

// ---------------------------------------------------------------------------
extern "C" void kernel_launch(void* const* d_in, const int* in_sizes, int n_in,
                              void* d_out, int out_size, void* d_ws, size_t ws_size,
                              hipStream_t stream) {
  const float* X      = (const float*)d_in[0];
  const float* A      = (const float*)d_in[1];
  const float* W_eps  = (const float*)d_in[2];
  const float* W_mu   = (const float*)d_in[3];
  const float* W_lv   = (const float*)d_in[4];
  const float* pW_mu  = (const float*)d_in[5];
  const float* pW_lv  = (const float*)d_in[6];
  const float* enc_w1 = (const float*)d_in[7];
  const float* enc_b1 = (const float*)d_in[8];
  const float* enc_w2 = (const float*)d_in[9];
  const float* enc_b2 = (const float*)d_in[10];
  const float* gw_ih  = (const float*)d_in[11];
  const float* gw_hh  = (const float*)d_in[12];
  const float* gb_ih  = (const float*)d_in[13];
  const float* gb_hh  = (const float*)d_in[14];
  const float* dec_w  = (const float*)d_in[15];
  const float* dec_b  = (const float*)d_in[16];
  const float* em_w   = (const float*)d_in[17];
  const float* em_b   = (const float*)d_in[18];
  const float* ev_w   = (const float*)d_in[19];
  const float* ev_b   = (const float*)d_in[20];
  float* out = (float*)d_out;

  char* base = (char*)d_ws;
  size_t off = 0;
  auto alloc = [&](size_t bytes) -> void* {
    void* p = base + off;
    off += (bytes + 255) & ~(size_t)255;
    return p;
  };
  float* sigma          = (float*)alloc((size_t)H * HP * 4);
  float* hbuf           = (float*)alloc((size_t)BATCH * H * 4);
  unsigned short* hb    = (unsigned short*)alloc((size_t)BATCH * H * 2);
  float* fbuf           = (float*)alloc((size_t)BATCH * H * 4);
  float* Pbuf           = (float*)alloc((size_t)BATCH * 64 * 4);
  float* accb           = (float*)alloc(2 * 4);
  unsigned short* gwhhb = (unsigned short*)alloc((size_t)G3 * H * 2);
  unsigned short* decwb = (unsigned short*)alloc((size_t)H * H * 2);
  unsigned short* headwb= (unsigned short*)alloc((size_t)64 * H * 2);
  unsigned short* Wlast = (unsigned short*)alloc((size_t)BATCH * H * 2);
  unsigned short* Wm    = (unsigned short*)alloc((size_t)BATCH * H * 1024 * 2);

  hipMemsetAsync(accb, 0, 2 * sizeof(float), stream);
  hipMemsetAsync(Pbuf, 0, (size_t)BATCH * 64 * 4, stream);

  kl_sigma<<<(H * HP + 255) / 256, 256, 0, stream>>>(W_lv, pW_mu, pW_lv, W_mu, sigma, accb + 1);
  cvt_bf16<<<(G3 * H) / 256, 256, 0, stream>>>(gw_hh, gwhhb, G3 * H);
  cvt_bf16<<<(H * H) / 256, 256, 0, stream>>>(dec_w, decwb, H * H);
  cvt_bf16<<<(OUTD * H) / 256, 256, 0, stream>>>(em_w, headwb, OUTD * H);
  cvt_bf16<<<(OUTD * H) / 256, 256, 0, stream>>>(ev_w, headwb + OUTD * H, OUTD * H);
  gen_w<<<BATCH * H, 256, 0, stream>>>(W_eps, W_mu, sigma, Wm, Wlast);

  // encoder: fbuf = relu(X0 @ enc_w1^T + b1); hbuf = tanh(fbuf @ enc_w2^T + b2)
  gemm_nt<1><<<dim3(H / 32, BATCH / 32), 256, 0, stream>>>(X, enc_w1, enc_b1, fbuf,
                                                           BATCH, H, OUTD);
  gemm_nt<2><<<dim3(H / 32, BATCH / 32), 256, 0, stream>>>(fbuf, enc_w2, enc_b2, hbuf,
                                                           BATCH, H, H);
  cvt_bf16<<<(BATCH * H) / 256, 256, 0, stream>>>(hbuf, hb, BATCH * H);

  for (int t = 1; t <= TSTEPS; ++t) {
    const float* a_t = A + (size_t)(t - 1) * BATCH * ACTD;
    const float* Xprev = X + (size_t)(t - 1) * BATCH * OUTD;  // target for step t-1
    const int grid1 = (t == 1) ? 128 : 160;
    step_fused<<<grid1, 256, 0, stream>>>(hb, hbuf, gwhhb, gw_ih, gb_ih, gb_hh, a_t,
                                          fbuf, decwb, dec_b, headwb, Pbuf, 128);
    wmatvec2<<<8193, 256, 0, stream>>>((const u32x4v*)Wm, Wlast, fbuf, hbuf, hb, Pbuf,
                                       em_b, ev_b, Xprev, accb, (t >= 2) ? 1 : 0);
  }
  // dec/heads for the last step (t'=255)
  step_fused<<<32, 256, 0, stream>>>(hb, hbuf, gwhhb, gw_ih, gb_ih, gb_hh, A,
                                     fbuf, decwb, dec_b, headwb, Pbuf, 0);
  finalize<<<1, 256, 0, stream>>>(accb, Pbuf, em_b, ev_b,
                                  X + (size_t)TSTEPS * BATCH * OUTD, out);
}